// Round 8
// baseline (161.124 us; speedup 1.0000x reference)
//
#include <hip/hip_runtime.h>

// ---------------- problem constants ----------------
#define NB        8
#define NPB       120000
#define NPTS      (NB * NPB)       // 960000
#define MAX_PTS   10
#define MAX_VOX   40000
#define GX        704
#define GY        800
#define GZ        20

// R8: pure-read leadership resolution, 5 dispatches.
// Claim: every valid point plain-stores idx into TWO tables (independent
// hashes, both 2^18 u32/batch, no init needed -- every slot read was written
// by the reader itself). A cell is "claimed" if it wins slot A (else slot B);
// claimer = the winning idx. Losers of both (~2.6%) are "deferred".
// Colliders of claimed cells + all deferred points atomicMin into a small
// slab (~25k atomics total). KEY CHANGE vs R7: the claimer never folds --
// true leader = min(claimer_idx, slab_min). That makes final resolution a
// PURE READ of settled state, so resolve + in-tile rank + tile sums + mlist
// appends all fuse into one kernel (k_p2c). No promote/demote writes.
// Output: full 160B rows written in k_finish with CACHED stores (contiguous
// ~35KB/tile regions, L2-combined). R5's init-NT-zero + scattered row0 was
// hidden write-amplification (partial 16B islands at 160B stride -> ~40MB
// fetch-merge); reverted to the R0-R3 proven full-row scheme.
#define T0        (1 << 18)
#define T0MASK    (T0 - 1)

#define HC2       (1 << 15)        // slab (min-hash) slots per batch
#define HMASK2    (HC2 - 1)
#define NSLOT2    (NB * HC2)       // 262,144 slots, 2 MB

#define TILES     469              // ceil(120000 / 256)
#define TILES_PAD 512
#define MBCAP     8192             // per-batch multi list capacity (~500 expected)
#define MTILE     2048

#define EMPTY64   0xFFFFFFFFFFFFFFFFull

// output layout (flat float32)
#define OUT_VOX   0LL
#define OUT_NUM   12800000LL
#define OUT_COOR  13120000LL
#define OUT_GRID  14400000LL

__device__ __forceinline__ bool point_cell(const float* __restrict__ p,
                                           int& cx, int& cy, int& cz) {
    // must match numpy f32: floor((xyz - PC_MIN) / VSIZE)
    cx = (int)floorf((p[1] - 0.0f)   / 0.1f);
    cy = (int)floorf((p[2] - (-40.0f)) / 0.1f);
    cz = (int)floorf((p[3] - (-3.0f))  / 0.2f);
    return (cx >= 0) & (cx < GX) & (cy >= 0) & (cy < GY) & (cz >= 0) & (cz < GZ);
}

__device__ __forceinline__ unsigned hashA(int lid) {
    return (((unsigned)lid * 2654435761u) >> 14) & T0MASK;
}
__device__ __forceinline__ unsigned hashB(int lid) {
    return (((unsigned)lid * 0x9E3779B1u) >> 13) & T0MASK;
}
__device__ __forceinline__ unsigned slab_hash(int lid) {
    return (((unsigned)lid * 2654435761u) >> 17) & HMASK2;
}

// robin-hood atomicMin insert into the per-batch slab (min idx per cell).
// Slot values only decrease, entries only move forward -> settled-state
// lookups probe from home slot to first EMPTY with no gaps.
__device__ __forceinline__ void slab_insert(unsigned long long* __restrict__ base,
                                            int lid, int idx) {
    unsigned long long key = ((unsigned long long)(unsigned)lid << 32)
                           | (unsigned long long)(unsigned)idx;
    unsigned h = slab_hash(lid);
    while (true) {
        unsigned long long oo = atomicMin(base + h, key);
        if (oo == EMPTY64) break;                  // filled empty slot
        if ((oo >> 32) == (key >> 32)) break;      // same cell: min folded
        if (oo > key) key = oo;                    // displaced foreign: carry forward
        h = (h + 1) & HMASK2;
    }
}

// settled-slab lookup: returns min idx for cell, or 0xFFFFFFFF if no entry
__device__ __forceinline__ unsigned slab_find(const unsigned long long* __restrict__ base,
                                              int lid) {
    unsigned h = slab_hash(lid);
    while (true) {
        unsigned long long cur = base[h];
        if (cur == EMPTY64) return 0xFFFFFFFFu;
        if ((unsigned)(cur >> 32) == (unsigned)lid) return (unsigned)cur;
        h = (h + 1) & HMASK2;
    }
}

// ---------------- K0: lid + dual claim stores + slab init + mcount + grid ----------------
// Claims are plain scattered u32 stores (posted, no round trip). tblA/tblB
// need no init. XCD swizzle: batch = blockIdx & 7 keeps batch b's tables
// L2-local under round-robin dispatch (heuristic, correctness-independent).
__global__ void k_init(const float* __restrict__ pts, float* __restrict__ out,
                       ulonglong2* __restrict__ slab2, unsigned* __restrict__ tblA,
                       unsigned* __restrict__ tblB, int* __restrict__ lid32,
                       unsigned* __restrict__ mcount) {
    int b = blockIdx.x & 7;
    int idx = (blockIdx.x >> 3) * 256 + threadIdx.x;
    if (idx < NPB) {
        int g = b * NPB + idx;
        const float* p = pts + (long long)g * 5;
        int cx, cy, cz;
        if (point_cell(p, cx, cy, cz)) {
            int lid = (cz * GY + cy) * GX + cx;
            lid32[g] = lid;
            tblA[b * T0 + hashA(lid)] = (unsigned)idx;   // last-writer-wins claims
            tblB[b * T0 + hashB(lid)] = (unsigned)idx;
        } else {
            lid32[g] = -1;
        }
    }
    int t = blockIdx.x * 256 + threadIdx.x;              // 960,512 threads
    if (t < NSLOT2 / 2) {
        ulonglong2 e2; e2.x = EMPTY64; e2.y = EMPTY64;
        slab2[t] = e2;                                   // 2 MB
    }
    if (t < NB) mcount[t * 16] = 0u;
    if (t == 0) {
        out[OUT_GRID + 0] = 704.f;
        out[OUT_GRID + 1] = 800.f;
        out[OUT_GRID + 2] = 20.f;
    }
}

// ---------------- K1: classify via claim tables; colliders/deferred -> slab ----------------
// flag: 0=invalid, 1=claimer, 4=collider (cell claimed, self not claimer),
// 3=deferred (cell lost both slots, ~2.6% of cells).
__global__ void k_l0(const int* __restrict__ lid32, const unsigned* __restrict__ tblA,
                     const unsigned* __restrict__ tblB, unsigned char* __restrict__ flag,
                     unsigned long long* __restrict__ slabB) {
    int b = blockIdx.x & 7;
    int idx = (blockIdx.x >> 3) * 256 + threadIdx.x;
    if (idx >= NPB) return;
    int g = b * NPB + idx;
    int lid = lid32[g];
    if (lid < 0) { flag[g] = 0; return; }
    unsigned w = tblA[b * T0 + hashA(lid)];              // stable post-k_init
    if (lid32[b * NPB + (int)w] == lid) {                // claimed at A
        if (w == (unsigned)idx) { flag[g] = 1; return; }
        flag[g] = 4;
        slab_insert(slabB + (size_t)b * HC2, lid, idx);
        return;
    }
    w = tblB[b * T0 + hashB(lid)];                       // second chance at B
    if (lid32[b * NPB + (int)w] == lid) {
        if (w == (unsigned)idx) { flag[g] = 1; return; }
        flag[g] = 4;
        slab_insert(slabB + (size_t)b * HC2, lid, idx);
        return;
    }
    flag[g] = 3;                                         // deferred
    slab_insert(slabB + (size_t)b * HC2, lid, idx);
}

// ---------------- K2: pure-read resolve + in-tile rank + tileSum + mlist ----------------
// Slab and tables are settled (no writes since k_l0) -> every thread computes
// its own final leadership with reads only:
//   claimer:  leader = min(own idx, slab_min)        (slab_min = colliders' min)
//   collider: leader = min(claimer idx, slab_min)    (slab entry incl. self)
//   deferred: leader = slab_min                      (all points inserted)
// Exactly one point per cell sees leader==own. Non-leaders append mlist here.
// Block == tile: LDS scan produces in-tile leader rank + tile sum.
__global__ void k_p2c(const int* __restrict__ lid32, const unsigned* __restrict__ tblA,
                      const unsigned* __restrict__ tblB,
                      const unsigned long long* __restrict__ slabB,
                      unsigned char* __restrict__ flag, unsigned char* __restrict__ rank8,
                      int* __restrict__ tileSum, int2* __restrict__ mlist,
                      unsigned* __restrict__ mcount) {
    int b = blockIdx.x & 7;
    int tile = blockIdx.x >> 3;
    int t = threadIdx.x;
    int idx = tile * 256 + t;
    int g = b * NPB + idx;
    int f = 0;
    if (idx < NPB) {
        unsigned char pf = flag[g];
        if (pf) {
            int lid = lid32[g];
            const unsigned long long* base = slabB + (size_t)b * HC2;
            unsigned smin = slab_find(base, lid);        // 0xFFFFFFFF if absent
            unsigned leader;
            if (pf == 1) {                               // claimer
                leader = (smin < (unsigned)idx) ? smin : (unsigned)idx;
            } else if (pf == 4) {                        // collider: recover claimer idx
                unsigned w = tblA[b * T0 + hashA(lid)];
                if (lid32[b * NPB + (int)w] != lid) w = tblB[b * T0 + hashB(lid)];
                leader = (smin < w) ? smin : w;
            } else {                                     // deferred (pf == 3)
                leader = smin;
            }
            if (leader == (unsigned)idx) {
                f = 1;
            } else {                                     // multi-cell non-leader (~480/batch)
                unsigned m = atomicAdd(&mcount[b * 16], 1u);
                if (m < MBCAP) mlist[(size_t)b * MBCAP + m] = make_int2((int)leader, idx);
            }
        }
    }
    __shared__ int sc[256];
    sc[t] = f;
    __syncthreads();
    for (int off = 1; off < 256; off <<= 1) {
        int x = sc[t];
        if (t >= off) x += sc[t - off];
        __syncthreads();
        sc[t] = x;
        __syncthreads();
    }
    if (idx < NPB) {
        flag[g] = (unsigned char)f;
        rank8[g] = (unsigned char)(sc[t] - f);           // exclusive in-tile rank
    }
    if (t == 255) tileSum[b * TILES_PAD + tile] = sc[255];
}

// ---------------- K3: tile-sum scan + leader full-row writes ----------------
// Each block redundantly scans the 469 tile sums (1.9 KB, L2-hot). Leaders
// write the FULL 160B row (point + 9 zero rows), coors, num, slotOf with
// cached stores: consecutive leaders -> consecutive slots -> contiguous
// ~35KB/tile regions, L2 write-combined, no partial-line RMW.
__global__ void k_finish(const float* __restrict__ pts, const int* __restrict__ lid32,
                         const unsigned char* __restrict__ flag,
                         const unsigned char* __restrict__ rank8,
                         const int* __restrict__ tileSum,
                         float* __restrict__ out, unsigned short* __restrict__ slotOf) {
    int b = blockIdx.x & 7;
    int tile = blockIdx.x >> 3;
    int t = threadIdx.x;

    __shared__ int sc[256];
    __shared__ int soff[TILES_PAD];
    int v0 = (2 * t     < TILES) ? tileSum[b * TILES_PAD + 2 * t]     : 0;
    int v1 = (2 * t + 1 < TILES) ? tileSum[b * TILES_PAD + 2 * t + 1] : 0;
    int w = v0 + v1;
    sc[t] = w;
    __syncthreads();
    for (int off = 1; off < 256; off <<= 1) {
        int x = sc[t];
        if (t >= off) x += sc[t - off];
        __syncthreads();
        sc[t] = x;
        __syncthreads();
    }
    int e = sc[t] - w;
    soff[2 * t] = e;
    soff[2 * t + 1] = e + v0;
    __syncthreads();

    int idx = tile * 256 + t;
    if (idx >= NPB) return;
    int g = b * NPB + idx;
    if (!flag[g]) return;                      // leaders only

    int slot = soff[tile] + (int)rank8[g];
    slotOf[g] = (unsigned short)(slot < 65535 ? slot : 65535);  // before clip!
    if (slot >= MAX_VOX) return;
    int lid = lid32[g];
    unsigned ul = (unsigned)lid;
    unsigned cx = ul % (unsigned)GX;
    unsigned tt = ul / (unsigned)GX;
    unsigned cy = tt % (unsigned)GY;
    unsigned cz = tt / (unsigned)GY;
    long long r = (long long)b * MAX_VOX + slot;
    ((float4*)(out + OUT_COOR))[r] = make_float4((float)b, (float)cz, (float)cy, (float)cx);
    out[OUT_NUM + r] = 1.f;                    // multi corrected by k_multi
    const float* p = pts + (long long)g * 5;
    float4* row = (float4*)(out + OUT_VOX) + (size_t)r * MAX_PTS;
    row[0] = make_float4(p[1], p[2], p[3], p[4]);
    float4 zf = make_float4(0.f, 0.f, 0.f, 0.f);
    #pragma unroll
    for (int i = 1; i < MAX_PTS; i++) row[i] = zf;
}

// ---------------- K4: rank + scatter multi-cell non-leaders; fix num ----------------
// mlist entries are (leaderIdx, idx), leader never in list; slot via slotOf.
__global__ void k_multi(const float* __restrict__ pts,
                        const int2* __restrict__ mlist, const unsigned* __restrict__ mcount,
                        const unsigned short* __restrict__ slotOf,
                        float* __restrict__ out) {
    int b = blockIdx.y;
    unsigned n = mcount[b * 16];
    if (n > MBCAP) n = MBCAP;
    unsigned t = blockIdx.x * blockDim.x + threadIdx.x;
    const int2* lst = mlist + (size_t)b * MBCAP;
    bool active = (t < n);
    int2 e = active ? lst[t] : make_int2(-1, -1);   // (leaderIdx, idx)
    int pos = 1;                                    // leader (not in list) is pos 0
    int same = 0;                                   // same-cell entries incl. self
    __shared__ int2 sm[MTILE];
    for (unsigned chunk = 0; chunk < n; chunk += MTILE) {
        unsigned m = n - chunk;
        if (m > MTILE) m = MTILE;
        for (unsigned i = threadIdx.x; i < m; i += 256)
            sm[i] = lst[chunk + i];
        __syncthreads();
        if (active) {
            #pragma unroll 4
            for (unsigned j = 0; j < m; j++) {
                int2 o = sm[j];
                if (o.x == e.x) { same++; if (o.y < e.y) pos++; }
            }
        }
        __syncthreads();
    }
    if (!active) return;
    int slot = (int)slotOf[(size_t)b * NPB + e.x];
    if (slot >= MAX_VOX) return;
    if (pos == 1) {                                 // smallest non-leader writes true count
        int cnt = same + 1;                         // + leader
        out[OUT_NUM + (long long)b * MAX_VOX + slot] =
            (float)(cnt < MAX_PTS ? cnt : MAX_PTS);
    }
    if (pos >= MAX_PTS) return;
    const float* p = pts + ((long long)b * NPB + e.y) * 5;
    ((float4*)(out + OUT_VOX))[(long long)(b * MAX_VOX + slot) * MAX_PTS + pos] =
        make_float4(p[1], p[2], p[3], p[4]);
}

extern "C" void kernel_launch(void* const* d_in, const int* in_sizes, int n_in,
                              void* d_out, int out_size, void* d_ws, size_t ws_size,
                              hipStream_t stream) {
    const float* pts = (const float*)d_in[0];
    float* out = (float*)d_out;

    char* w = (char*)d_ws;
    unsigned* tblA = (unsigned*)w;            w += (size_t)NB * T0 * 4;    // 8 MB (no init)
    unsigned* tblB = (unsigned*)w;            w += (size_t)NB * T0 * 4;    // 8 MB (no init)
    unsigned long long* slabB = (unsigned long long*)w;
    w += (size_t)NSLOT2 * 8;                                               // 2 MB
    int2* mlist = (int2*)w;  w += (size_t)NB * MBCAP * 8;                  // 0.5 MB
    int* lid32 = (int*)w;    w += (size_t)NPTS * 4;                        // 3.84 MB
    int* tileSum = (int*)w;  w += (size_t)NB * TILES_PAD * 4;              // 16 KB
    unsigned* mcount = (unsigned*)w; w += (size_t)NB * 16 * 4;             // 512 B
    unsigned short* slotOf = (unsigned short*)w; w += (size_t)NPTS * 2;    // 1.92 MB
    unsigned char* flag = (unsigned char*)w;  w += (size_t)NPTS;           // 0.96 MB
    unsigned char* rank8 = (unsigned char*)w; w += (size_t)NPTS;           // 0.96 MB

    const int PB = TILES * NB;      // 3752 blocks for per-point kernels
    k_init<<<dim3(PB), dim3(256), 0, stream>>>(pts, out, (ulonglong2*)slabB,
                                               tblA, tblB, lid32, mcount);
    k_l0<<<dim3(PB), dim3(256), 0, stream>>>(lid32, tblA, tblB, flag, slabB);
    k_p2c<<<dim3(PB), dim3(256), 0, stream>>>(lid32, tblA, tblB, slabB,
                                              flag, rank8, tileSum, mlist, mcount);
    k_finish<<<dim3(PB), dim3(256), 0, stream>>>(pts, lid32, flag, rank8, tileSum,
                                                 out, slotOf);
    k_multi<<<dim3(MBCAP / 256, NB), dim3(256), 0, stream>>>(pts, mlist, mcount, slotOf, out);
}